// Round 7
// baseline (120.815 us; speedup 1.0000x reference)
//
#include <hip/hip_runtime.h>
#include <math.h>

#define C_DIM 256
#define NH 8
#define HD 32
#define BATCH 2
#define NPIX 2304        // 48*48
#define TK 64
#define NGRP (NPIX / 16) // 144 n-groups of 16

typedef __attribute__((ext_vector_type(8))) short bf16x8;
typedef __attribute__((ext_vector_type(4))) float f32x4;

// workspace offsets (in shorts / uint16 elems)
#define OFF_XT  0u
#define OFF_Q   1179648u
#define OFF_K   2359296u
#define OFF_V   3538944u
#define OFF_OT  4718592u
#define OFF_WQ  5898240u
#define OFF_WP  6094848u

__device__ __forceinline__ unsigned short f2b(float f) {
    union { float f; unsigned int u; } c; c.f = f;
    unsigned int u = c.u + 0x7FFFu + ((c.u >> 16) & 1u);
    return (unsigned short)(u >> 16);
}
__device__ __forceinline__ unsigned int pk2(float lo, float hi) {
    union { float f; unsigned int u; } a, b;
    a.f = lo; b.f = hi;
    return __builtin_amdgcn_perm(b.u + 0x8000u, a.u + 0x8000u, 0x07060302u);
}

// ---------------------------------------------------------------------------
// Prep A: x [b][c][n] f32 -> xT bf16 in FRAGMENT-MAJOR cells:
// cell(b, ngrp=n>>4, j=c>>3) = 16 lanes(n&15) x 8 shorts (c j*8..j*8+7).
// 64x64 tile via LDS. grid (36, 4, 2), block 256.
// ---------------------------------------------------------------------------
__global__ __launch_bounds__(256) void prep_xt(
        const float* __restrict__ x, unsigned short* __restrict__ xT)
{
    __shared__ unsigned short t_s[64][72];
    const int tid = threadIdx.x;
    const int n0 = blockIdx.x * 64, c0 = blockIdx.y * 64, b = blockIdx.z;
    const int nl = tid & 63, cq = tid >> 6;
    #pragma unroll
    for (int p = 0; p < 8; ++p) {
        const int c = p * 8 + cq * 2;
        const float f0 = x[((size_t)b * C_DIM + c0 + c) * NPIX + n0 + nl];
        const float f1 = x[((size_t)b * C_DIM + c0 + c + 1) * NPIX + n0 + nl];
        *(unsigned int*)&t_s[nl][c] = pk2(f0, f1);
    }
    __syncthreads();
    const int row = tid >> 2, jq = tid & 3;
    #pragma unroll
    for (int hh = 0; hh < 2; ++hh) {
        const int jl = jq * 2 + hh;
        const int jg = blockIdx.y * 8 + jl;            // c>>3, 0..31
        const int ngrp = blockIdx.x * 4 + (row >> 4);
        unsigned short* dst = xT + (((size_t)b * NGRP + ngrp) * 32 + jg) * 128 + (row & 15) * 8;
        *(uint4*)dst = *(uint4*)&t_s[row][jl * 8];
    }
}

// ---------------------------------------------------------------------------
// Prep B: w_qkv [768][256], w_proj [256][256] f32 -> bf16 fragment-major
// cells ((m>>4)*32 + (c>>3))*16 + (m&15). grid 128, block 256.
// ---------------------------------------------------------------------------
__global__ __launch_bounds__(256) void prep_w(
        const float* __restrict__ wqkv, const float* __restrict__ wproj,
        unsigned short* __restrict__ wq, unsigned short* __restrict__ wp)
{
    const int t = blockIdx.x * 256 + threadIdx.x;   // 0..32767
    const float* src; unsigned short* dst;
    if (t < 24576) {
        const int m = t >> 5, j = t & 31;
        src = wqkv + ((size_t)m * C_DIM + j * 8);
        dst = wq + ((size_t)((m >> 4) * 32 + j) * 16 + (m & 15)) * 8;
    } else {
        const int t2 = t - 24576, m = t2 >> 5, j = t2 & 31;
        src = wproj + ((size_t)m * C_DIM + j * 8);
        dst = wp + ((size_t)((m >> 4) * 32 + j) * 16 + (m & 15)) * 8;
    }
    const float4 f0 = *(const float4*)src, f1 = *(const float4*)(src + 4);
    *(uint4*)dst = make_uint4(pk2(f0.x, f0.y), pk2(f0.z, f0.w),
                              pk2(f1.x, f1.y), pk2(f1.z, f1.w));
}

// ---------------------------------------------------------------------------
// Kernel 1: qkv GEMM, streaming: NO LDS staging, NO barriers. K=256 in regs.
// Block 256 = 4 waves; block tile m=16 (my), n=256 (wave 64, 4 subtiles).
// grid (9, 48, 2). Coalesced epilogues via per-wave LDS micro-transpose.
// ---------------------------------------------------------------------------
__global__ __launch_bounds__(256) void qkv_gemm(
        const unsigned short* __restrict__ xT, const unsigned short* __restrict__ wq,
        const float* __restrict__ bias,
        unsigned short* __restrict__ Qg, unsigned short* __restrict__ Kg,
        unsigned short* __restrict__ Vg)
{
    __shared__ unsigned short eplds[4][2560];   // 5.1 KB per wave
    const int tid = threadIdx.x, wv = tid >> 6, lane = tid & 63;
    const int l15 = lane & 15, quad = lane >> 4;
    const int n0 = blockIdx.x * 256, my = blockIdx.y, b = blockIdx.z;
    const int nw = n0 + wv * 64;

    bf16x8 af[8];
    #pragma unroll
    for (int kc = 0; kc < 8; ++kc)
        af[kc] = *(const bf16x8*)(wq + ((size_t)(my * 32 + kc * 4 + quad) * 16 + l15) * 8);

    f32x4 acc[4];
    #pragma unroll
    for (int i = 0; i < 4; ++i) acc[i] = (f32x4){0.f, 0.f, 0.f, 0.f};

    #pragma unroll
    for (int sub = 0; sub < 4; ++sub) {
        const int ngrp = (nw + sub * 16) >> 4;
        const unsigned short* bp = xT + ((size_t)b * NGRP + ngrp) * 32 * 128;
        #pragma unroll
        for (int kc = 0; kc < 8; ++kc) {
            const bf16x8 bf = *(const bf16x8*)(bp + (size_t)(kc * 4 + quad) * 128 + l15 * 8);
            acc[sub] = __builtin_amdgcn_mfma_f32_16x16x32_bf16(af[kc], bf, acc[sub], 0, 0, 0);
        }
    }

    const int which = my >> 4;              // 0=q, 1=k, 2=v (block-uniform)
    const int ch0 = (my & 15) * 16;
    const int h = ch0 >> 5, d0 = ch0 & 31, bh = b * NH + h;
    const float4 b4 = *(const float4*)(bias + my * 16 + quad * 4);
    unsigned short* wl = eplds[wv];

    if (which < 2) {
        const float sc = (which == 0) ? 0.17677669529663687f : 1.0f;
        #pragma unroll
        for (int sub = 0; sub < 4; ++sub) {
            const float v0 = (acc[sub][0] + b4.x) * sc, v1 = (acc[sub][1] + b4.y) * sc;
            const float v2 = (acc[sub][2] + b4.z) * sc, v3 = (acc[sub][3] + b4.w) * sc;
            *(uint2*)&wl[(sub * 16 + l15) * 40 + quad * 4] =
                make_uint2(pk2(v0, v1), pk2(v2, v3));
        }
        unsigned short* dst = ((which == 0) ? Qg : Kg)
                            + ((size_t)bh * NPIX + nw + lane) * HD + d0;
        *(uint4*)dst       = *(uint4*)&wl[lane * 40];
        *(uint4*)(dst + 8) = *(uint4*)&wl[lane * 40 + 8];
    } else {
        #pragma unroll
        for (int sub = 0; sub < 4; ++sub) {
            wl[(quad * 4 + 0) * 72 + sub * 16 + l15] = f2b(acc[sub][0] + b4.x);
            wl[(quad * 4 + 1) * 72 + sub * 16 + l15] = f2b(acc[sub][1] + b4.y);
            wl[(quad * 4 + 2) * 72 + sub * 16 + l15] = f2b(acc[sub][2] + b4.z);
            wl[(quad * 4 + 3) * 72 + sub * 16 + l15] = f2b(acc[sub][3] + b4.w);
        }
        #pragma unroll
        for (int p = 0; p < 2; ++p) {
            const int row = p * 8 + (lane >> 3), cn = (lane & 7) * 8;
            *(uint4*)(Vg + ((size_t)bh * HD + d0 + row) * NPIX + nw + cn) =
                *(uint4*)&wl[row * 72 + cn];
        }
    }
}

// ---------------------------------------------------------------------------
// Kernel 2: MFMA flash attention (round-6 structure). Emits OtT bf16
// fragment-major for the streaming proj. grid (16, 36).
// ---------------------------------------------------------------------------
#define NT (NPIX / TK)

__global__ __launch_bounds__(256) void attn_kernel(
        const unsigned short* __restrict__ Qg, const unsigned short* __restrict__ Kg,
        const unsigned short* __restrict__ Vg, unsigned short* __restrict__ OtT)
{
    __shared__ unsigned short k_s[2][TK][40];
    __shared__ unsigned short v_s[2][HD][76];
    __shared__ unsigned short p_s[4][16][76];
    __shared__ unsigned short o_sT[64][40];

    const int tid  = threadIdx.x;
    const int wv   = tid >> 6;
    const int lane = tid & 63;
    const int l15  = lane & 15;
    const int quad = lane >> 4;
    const int bh   = blockIdx.x;           // XCD-pinned
    const int q0   = blockIdx.y * 64;

    const unsigned short* Qh = Qg + (size_t)bh * NPIX * HD;
    const unsigned short* Kh = Kg + (size_t)bh * NPIX * HD;
    const unsigned short* Vh = Vg + (size_t)bh * HD * NPIX;

    const bf16x8 q_frag = *(const bf16x8*)(Qh + (size_t)(q0 + wv * 16 + l15) * HD + quad * 8);

    const int kr = tid >> 2, kc = (tid & 3) * 8;
    const int vd = tid >> 3, vc = (tid & 7) * 8;

    uint4 kreg = *(const uint4*)(Kh + (size_t)kr * HD + kc);
    uint4 vreg = *(const uint4*)(Vh + (size_t)vd * NPIX + vc);
    *(uint4*)&k_s[0][kr][kc] = kreg;
    *(uint4*)&v_s[0][vd][vc] = vreg;

    f32x4 o0 = {0.f, 0.f, 0.f, 0.f};
    f32x4 o1 = {0.f, 0.f, 0.f, 0.f};
    float lsum = 0.f;

    for (int t = 0; t < NT; ++t) {
        const int cur = t & 1;
        if (t + 1 < NT) {
            const int k0 = (t + 1) * TK;
            kreg = *(const uint4*)(Kh + (size_t)(k0 + kr) * HD + kc);
            vreg = *(const uint4*)(Vh + (size_t)vd * NPIX + k0 + vc);
        }
        __syncthreads();

        f32x4 s[4];
        #pragma unroll
        for (int kg = 0; kg < 4; ++kg) {
            const bf16x8 kf = *(const bf16x8*)&k_s[cur][kg * 16 + l15][quad * 8];
            s[kg] = __builtin_amdgcn_mfma_f32_16x16x32_bf16(kf, q_frag,
                        (f32x4){0.f, 0.f, 0.f, 0.f}, 0, 0, 0);
        }

        #pragma unroll
        for (int kg = 0; kg < 4; ++kg) {
            const float p0 = __expf(s[kg][0]);
            const float p1 = __expf(s[kg][1]);
            const float p2 = __expf(s[kg][2]);
            const float p3 = __expf(s[kg][3]);
            lsum += (p0 + p1) + (p2 + p3);
            *(uint2*)&p_s[wv][l15][kg * 16 + quad * 4] =
                make_uint2(pk2(p0, p1), pk2(p2, p3));
        }

        #pragma unroll
        for (int kc2 = 0; kc2 < 2; ++kc2) {
            const bf16x8 pf  = *(const bf16x8*)&p_s[wv][l15][kc2 * 32 + quad * 8];
            const bf16x8 vf0 = *(const bf16x8*)&v_s[cur][l15][kc2 * 32 + quad * 8];
            const bf16x8 vf1 = *(const bf16x8*)&v_s[cur][16 + l15][kc2 * 32 + quad * 8];
            o0 = __builtin_amdgcn_mfma_f32_16x16x32_bf16(vf0, pf, o0, 0, 0, 0);
            o1 = __builtin_amdgcn_mfma_f32_16x16x32_bf16(vf1, pf, o1, 0, 0, 0);
        }

        if (t + 1 < NT) {
            *(uint4*)&k_s[cur ^ 1][kr][kc] = kreg;
            *(uint4*)&v_s[cur ^ 1][vd][vc] = vreg;
        }
    }

    lsum += __shfl_xor(lsum, 16, 64);
    lsum += __shfl_xor(lsum, 32, 64);
    const float inv = 1.f / lsum;

    // O^T regs (rows d, cols q) -> o_sT [q][d] bf16 -> fragment-major OtT
    *(uint2*)&o_sT[wv * 16 + l15][quad * 4] =
        make_uint2(pk2(o0[0] * inv, o0[1] * inv), pk2(o0[2] * inv, o0[3] * inv));
    *(uint2*)&o_sT[wv * 16 + l15][16 + quad * 4] =
        make_uint2(pk2(o1[0] * inv, o1[1] * inv), pk2(o1[2] * inv, o1[3] * inv));
    __syncthreads();
    const int row = tid >> 2, jq = tid & 3;
    const int b = bh >> 3, h = bh & 7;
    const int q = q0 + row;
    unsigned short* dst = OtT + (((size_t)b * NGRP + (q >> 4)) * 32 + h * 4 + jq) * 128
                        + (q & 15) * 8;
    *(uint4*)dst = *(uint4*)&o_sT[row][jq * 8];
}

// ---------------------------------------------------------------------------
// Kernel 3: proj GEMM, streaming (no staging/barriers) + fused bias/residual.
// Block tile m=16, n=128 (wave 32, 2 subtiles). grid (18, 16, 2).
// ---------------------------------------------------------------------------
__global__ __launch_bounds__(256) void proj_gemm(
        const unsigned short* __restrict__ OtT, const unsigned short* __restrict__ wp,
        const float* __restrict__ bias, const float* __restrict__ x,
        float* __restrict__ out)
{
    __shared__ float plds[4][576];   // per-wave [16][36] f32
    const int tid = threadIdx.x, wv = tid >> 6, lane = tid & 63;
    const int l15 = lane & 15, quad = lane >> 4;
    const int n0 = blockIdx.x * 128, my = blockIdx.y, b = blockIdx.z;
    const int nw = n0 + wv * 32;

    bf16x8 af[8];
    #pragma unroll
    for (int kc = 0; kc < 8; ++kc)
        af[kc] = *(const bf16x8*)(wp + ((size_t)(my * 32 + kc * 4 + quad) * 16 + l15) * 8);

    f32x4 acc[2];
    acc[0] = (f32x4){0.f, 0.f, 0.f, 0.f};
    acc[1] = (f32x4){0.f, 0.f, 0.f, 0.f};

    #pragma unroll
    for (int sub = 0; sub < 2; ++sub) {
        const int ngrp = (nw + sub * 16) >> 4;
        const unsigned short* bp = OtT + ((size_t)b * NGRP + ngrp) * 32 * 128;
        #pragma unroll
        for (int kc = 0; kc < 8; ++kc) {
            const bf16x8 bf = *(const bf16x8*)(bp + (size_t)(kc * 4 + quad) * 128 + l15 * 8);
            acc[sub] = __builtin_amdgcn_mfma_f32_16x16x32_bf16(af[kc], bf, acc[sub], 0, 0, 0);
        }
    }

    float* wl = plds[wv];
    #pragma unroll
    for (int sub = 0; sub < 2; ++sub) {
        wl[(quad * 4 + 0) * 36 + sub * 16 + l15] = acc[sub][0];
        wl[(quad * 4 + 1) * 36 + sub * 16 + l15] = acc[sub][1];
        wl[(quad * 4 + 2) * 36 + sub * 16 + l15] = acc[sub][2];
        wl[(quad * 4 + 3) * 36 + sub * 16 + l15] = acc[sub][3];
    }
    const int m0 = my * 16;
    #pragma unroll
    for (int p = 0; p < 2; ++p) {
        const int row = p * 8 + (lane >> 3), cn = (lane & 7) * 4;
        const int c = m0 + row;
        const size_t idx = ((size_t)b * C_DIM + c) * NPIX + nw + cn;
        const f32x4 v = *(const f32x4*)&wl[row * 36 + cn];
        const f32x4 r = *(const f32x4*)(x + idx);
        const float bv = bias[c];
        f32x4 o;
        o[0] = v[0] + bv + r[0]; o[1] = v[1] + bv + r[1];
        o[2] = v[2] + bv + r[2]; o[3] = v[3] + bv + r[3];
        *(f32x4*)(out + idx) = o;
    }
}

// ---------------------------------------------------------------------------
extern "C" void kernel_launch(void* const* d_in, const int* in_sizes, int n_in,
                              void* d_out, int out_size, void* d_ws, size_t ws_size,
                              hipStream_t stream)
{
    const float* x      = (const float*)d_in[0];
    const float* w_qkv  = (const float*)d_in[1];
    const float* b_qkv  = (const float*)d_in[2];
    const float* w_proj = (const float*)d_in[3];
    const float* b_proj = (const float*)d_in[4];
    float* out = (float*)d_out;

    unsigned short* ws = (unsigned short*)d_ws;
    unsigned short* xT  = ws + OFF_XT;
    unsigned short* Qg  = ws + OFF_Q;
    unsigned short* Kg  = ws + OFF_K;
    unsigned short* Vg  = ws + OFF_V;
    unsigned short* OtT = ws + OFF_OT;
    unsigned short* wq  = ws + OFF_WQ;
    unsigned short* wp  = ws + OFF_WP;

    prep_xt<<<dim3(36, 4, 2), 256, 0, stream>>>(x, xT);
    prep_w<<<dim3(128), 256, 0, stream>>>(w_qkv, w_proj, wq, wp);
    qkv_gemm<<<dim3(9, 48, 2), 256, 0, stream>>>(xT, wq, b_qkv, Qg, Kg, Vg);
    attn_kernel<<<dim3(16, 36), 256, 0, stream>>>(Qg, Kg, Vg, OtT);
    proj_gemm<<<dim3(18, 16, 2), 256, 0, stream>>>(OtT, wp, b_proj, x, out);
}

// Round 8
// 117.862 us; speedup vs baseline: 1.0251x; 1.0251x over previous
//
#include <hip/hip_runtime.h>
#include <math.h>

#define C_DIM 256
#define NH 8
#define HD 32
#define BATCH 2
#define NPIX 2304        // 48*48
#define TK 64
#define NGRP (NPIX / 16) // 144 n-groups of 16
#define TPB 18           // K-tiles per attn block (split-K 2)

typedef __attribute__((ext_vector_type(8))) short bf16x8;
typedef __attribute__((ext_vector_type(4))) float f32x4;

// workspace offsets (in shorts)
#define OFF_XT  0u
#define OFF_Q   1179648u
#define OFF_K   2359296u
#define OFF_V   3538944u
#define OFF_OT  4718592u
#define OFF_WQ  5898240u
#define OFF_WP  6094848u
#define OFF_F32 6160384u   // float region starts here (even -> 4B aligned)

__device__ __forceinline__ unsigned short f2b(float f) {
    union { float f; unsigned int u; } c; c.f = f;
    unsigned int u = c.u + 0x7FFFu + ((c.u >> 16) & 1u);
    return (unsigned short)(u >> 16);
}
__device__ __forceinline__ unsigned int pk2(float lo, float hi) {
    union { float f; unsigned int u; } a, b;
    a.f = lo; b.f = hi;
    return __builtin_amdgcn_perm(b.u + 0x8000u, a.u + 0x8000u, 0x07060302u);
}

// ---------------------------------------------------------------------------
// Prep A: x [b][c][n] f32 -> xT bf16 fragment-major (unchanged). grid (36,4,2).
// ---------------------------------------------------------------------------
__global__ __launch_bounds__(256) void prep_xt(
        const float* __restrict__ x, unsigned short* __restrict__ xT)
{
    __shared__ unsigned short t_s[64][72];
    const int tid = threadIdx.x;
    const int n0 = blockIdx.x * 64, c0 = blockIdx.y * 64, b = blockIdx.z;
    const int nl = tid & 63, cq = tid >> 6;
    #pragma unroll
    for (int p = 0; p < 8; ++p) {
        const int c = p * 8 + cq * 2;
        const float f0 = x[((size_t)b * C_DIM + c0 + c) * NPIX + n0 + nl];
        const float f1 = x[((size_t)b * C_DIM + c0 + c + 1) * NPIX + n0 + nl];
        *(unsigned int*)&t_s[nl][c] = pk2(f0, f1);
    }
    __syncthreads();
    const int row = tid >> 2, jq = tid & 3;
    #pragma unroll
    for (int hh = 0; hh < 2; ++hh) {
        const int jl = jq * 2 + hh;
        const int jg = blockIdx.y * 8 + jl;
        const int ngrp = blockIdx.x * 4 + (row >> 4);
        unsigned short* dst = xT + (((size_t)b * NGRP + ngrp) * 32 + jg) * 128 + (row & 15) * 8;
        *(uint4*)dst = *(uint4*)&t_s[row][jl * 8];
    }
}

// ---------------------------------------------------------------------------
// Prep B: weights f32 -> bf16 fragment-major (unchanged). grid 128.
// ---------------------------------------------------------------------------
__global__ __launch_bounds__(256) void prep_w(
        const float* __restrict__ wqkv, const float* __restrict__ wproj,
        unsigned short* __restrict__ wq, unsigned short* __restrict__ wp)
{
    const int t = blockIdx.x * 256 + threadIdx.x;
    const float* src; unsigned short* dst;
    if (t < 24576) {
        const int m = t >> 5, j = t & 31;
        src = wqkv + ((size_t)m * C_DIM + j * 8);
        dst = wq + ((size_t)((m >> 4) * 32 + j) * 16 + (m & 15)) * 8;
    } else {
        const int t2 = t - 24576, m = t2 >> 5, j = t2 & 31;
        src = wproj + ((size_t)m * C_DIM + j * 8);
        dst = wp + ((size_t)((m >> 4) * 32 + j) * 16 + (m & 15)) * 8;
    }
    const float4 f0 = *(const float4*)src, f1 = *(const float4*)(src + 4);
    *(uint4*)dst = make_uint4(pk2(f0.x, f0.y), pk2(f0.z, f0.w),
                              pk2(f1.x, f1.y), pk2(f1.z, f1.w));
}

// ---------------------------------------------------------------------------
// Kernel 1: qkv GEMM, streaming, m=32 per block (4x less B re-read than m=16).
// Block 256 = 4 waves; tile m=32 (2 subtiles), n=256 (wave 64, 4 subtiles).
// grid (9, 24, 2): my 0..7=q, 8..15=k, 16..23=v (h = my&7, full d 0..31).
// ---------------------------------------------------------------------------
__global__ __launch_bounds__(256, 2) void qkv_gemm(
        const unsigned short* __restrict__ xT, const unsigned short* __restrict__ wq,
        const float* __restrict__ bias,
        unsigned short* __restrict__ Qg, unsigned short* __restrict__ Kg,
        unsigned short* __restrict__ Vg)
{
    __shared__ unsigned short eplds[4][2560];
    const int tid = threadIdx.x, wv = tid >> 6, lane = tid & 63;
    const int l15 = lane & 15, quad = lane >> 4;
    const int n0 = blockIdx.x * 256, my = blockIdx.y, b = blockIdx.z;
    const int nw = n0 + wv * 64;

    bf16x8 af[2][8];
    #pragma unroll
    for (int mt = 0; mt < 2; ++mt)
        #pragma unroll
        for (int kc = 0; kc < 8; ++kc)
            af[mt][kc] = *(const bf16x8*)(wq +
                ((size_t)((my * 2 + mt) * 32 + kc * 4 + quad) * 16 + l15) * 8);

    f32x4 acc[2][4];
    #pragma unroll
    for (int mt = 0; mt < 2; ++mt)
        #pragma unroll
        for (int s = 0; s < 4; ++s) acc[mt][s] = (f32x4){0.f, 0.f, 0.f, 0.f};

    #pragma unroll
    for (int sub = 0; sub < 4; ++sub) {
        const int ngrp = (nw + sub * 16) >> 4;
        const unsigned short* bp = xT + ((size_t)b * NGRP + ngrp) * 32 * 128;
        #pragma unroll
        for (int kc = 0; kc < 8; ++kc) {
            const bf16x8 bf = *(const bf16x8*)(bp + (size_t)(kc * 4 + quad) * 128 + l15 * 8);
            acc[0][sub] = __builtin_amdgcn_mfma_f32_16x16x32_bf16(af[0][kc], bf, acc[0][sub], 0, 0, 0);
            acc[1][sub] = __builtin_amdgcn_mfma_f32_16x16x32_bf16(af[1][kc], bf, acc[1][sub], 0, 0, 0);
        }
    }

    const int which = my >> 3;          // block-uniform: 0=q, 1=k, 2=v
    const int h = my & 7, bh = b * NH + h;
    float4 b4[2];
    b4[0] = *(const float4*)(bias + my * 32 + quad * 4);
    b4[1] = *(const float4*)(bias + my * 32 + 16 + quad * 4);
    unsigned short* wl = eplds[wv];

    if (which < 2) {
        const float sc = (which == 0) ? 0.17677669529663687f : 1.0f;
        #pragma unroll
        for (int mt = 0; mt < 2; ++mt)
            #pragma unroll
            for (int sub = 0; sub < 4; ++sub) {
                const float v0 = (acc[mt][sub][0] + b4[mt].x) * sc;
                const float v1 = (acc[mt][sub][1] + b4[mt].y) * sc;
                const float v2 = (acc[mt][sub][2] + b4[mt].z) * sc;
                const float v3 = (acc[mt][sub][3] + b4[mt].w) * sc;
                *(uint2*)&wl[(sub * 16 + l15) * 40 + mt * 16 + quad * 4] =
                    make_uint2(pk2(v0, v1), pk2(v2, v3));
            }
        unsigned short* dst = ((which == 0) ? Qg : Kg)
                            + ((size_t)bh * NPIX + nw + lane) * HD;
        #pragma unroll
        for (int i = 0; i < 4; ++i)
            *((uint4*)dst + i) = *(uint4*)&wl[lane * 40 + i * 8];
    } else {
        #pragma unroll
        for (int mt = 0; mt < 2; ++mt)
            #pragma unroll
            for (int sub = 0; sub < 4; ++sub) {
                wl[(mt * 16 + quad * 4 + 0) * 72 + sub * 16 + l15] = f2b(acc[mt][sub][0] + b4[mt].x);
                wl[(mt * 16 + quad * 4 + 1) * 72 + sub * 16 + l15] = f2b(acc[mt][sub][1] + b4[mt].y);
                wl[(mt * 16 + quad * 4 + 2) * 72 + sub * 16 + l15] = f2b(acc[mt][sub][2] + b4[mt].z);
                wl[(mt * 16 + quad * 4 + 3) * 72 + sub * 16 + l15] = f2b(acc[mt][sub][3] + b4[mt].w);
            }
        const int row = lane >> 1, seg = (lane & 1) * 32;
        unsigned short* dst = Vg + ((size_t)bh * HD + row) * NPIX + nw + seg;
        #pragma unroll
        for (int i = 0; i < 4; ++i)
            *((uint4*)dst + i) = *(uint4*)&wl[row * 72 + seg + i * 8];
    }
}

// ---------------------------------------------------------------------------
// Kernel 2: MFMA flash attention, split-K x2 (shift-0 softmax => partials
// combine by plain addition). Each block: 18 K-tiles, f32 partial O + lsum.
// grid (16, 36, 2): bh = blockIdx.x (XCD-pinned), q-block, split.
// ---------------------------------------------------------------------------
__global__ __launch_bounds__(256, 4) void attn_kernel(
        const unsigned short* __restrict__ Qg, const unsigned short* __restrict__ Kg,
        const unsigned short* __restrict__ Vg,
        float* __restrict__ OtP, float* __restrict__ lsumP)
{
    __shared__ unsigned short k_s[2][TK][40];
    __shared__ unsigned short v_s[2][HD][76];
    __shared__ unsigned short p_s[4][16][76];   // per-wave; reused f32 in epilogue

    const int tid  = threadIdx.x;
    const int wv   = tid >> 6;
    const int lane = tid & 63;
    const int l15  = lane & 15;
    const int quad = lane >> 4;
    const int bh   = blockIdx.x;
    const int q0   = blockIdx.y * 64;
    const int sp   = blockIdx.z;               // split 0/1
    const int t0   = sp * TPB;

    const unsigned short* Qh = Qg + (size_t)bh * NPIX * HD;
    const unsigned short* Kh = Kg + (size_t)bh * NPIX * HD;
    const unsigned short* Vh = Vg + (size_t)bh * HD * NPIX;

    const bf16x8 q_frag = *(const bf16x8*)(Qh + (size_t)(q0 + wv * 16 + l15) * HD + quad * 8);

    const int kr = tid >> 2, kc = (tid & 3) * 8;
    const int vd = tid >> 3, vc = (tid & 7) * 8;

    uint4 kreg = *(const uint4*)(Kh + (size_t)(t0 * TK + kr) * HD + kc);
    uint4 vreg = *(const uint4*)(Vh + (size_t)vd * NPIX + t0 * TK + vc);
    *(uint4*)&k_s[0][kr][kc] = kreg;
    *(uint4*)&v_s[0][vd][vc] = vreg;

    f32x4 o0 = {0.f, 0.f, 0.f, 0.f};
    f32x4 o1 = {0.f, 0.f, 0.f, 0.f};
    float lsum = 0.f;

    for (int t = 0; t < TPB; ++t) {
        const int cur = t & 1;
        if (t + 1 < TPB) {
            const int k0 = (t0 + t + 1) * TK;
            kreg = *(const uint4*)(Kh + (size_t)(k0 + kr) * HD + kc);
            vreg = *(const uint4*)(Vh + (size_t)vd * NPIX + k0 + vc);
        }
        __syncthreads();

        f32x4 s[4];
        #pragma unroll
        for (int kg = 0; kg < 4; ++kg) {
            const bf16x8 kf = *(const bf16x8*)&k_s[cur][kg * 16 + l15][quad * 8];
            s[kg] = __builtin_amdgcn_mfma_f32_16x16x32_bf16(kf, q_frag,
                        (f32x4){0.f, 0.f, 0.f, 0.f}, 0, 0, 0);
        }

        #pragma unroll
        for (int kg = 0; kg < 4; ++kg) {
            const float p0 = __expf(s[kg][0]);
            const float p1 = __expf(s[kg][1]);
            const float p2 = __expf(s[kg][2]);
            const float p3 = __expf(s[kg][3]);
            lsum += (p0 + p1) + (p2 + p3);
            *(uint2*)&p_s[wv][l15][kg * 16 + quad * 4] =
                make_uint2(pk2(p0, p1), pk2(p2, p3));
        }

        #pragma unroll
        for (int kc2 = 0; kc2 < 2; ++kc2) {
            const bf16x8 pf  = *(const bf16x8*)&p_s[wv][l15][kc2 * 32 + quad * 8];
            const bf16x8 vf0 = *(const bf16x8*)&v_s[cur][l15][kc2 * 32 + quad * 8];
            const bf16x8 vf1 = *(const bf16x8*)&v_s[cur][16 + l15][kc2 * 32 + quad * 8];
            o0 = __builtin_amdgcn_mfma_f32_16x16x32_bf16(vf0, pf, o0, 0, 0, 0);
            o1 = __builtin_amdgcn_mfma_f32_16x16x32_bf16(vf1, pf, o1, 0, 0, 0);
        }

        if (t + 1 < TPB) {
            *(uint4*)&k_s[cur ^ 1][kr][kc] = kreg;
            *(uint4*)&v_s[cur ^ 1][vd][vc] = vreg;
        }
    }

    lsum += __shfl_xor(lsum, 16, 64);
    lsum += __shfl_xor(lsum, 32, 64);

    // per-wave f32 transpose (reuse p_s region; barrier orders prior LDS use)
    __syncthreads();
    float* pp = (float*)&p_s[wv][0][0];        // [16 q][36 pitch] f32, 2304 B
    #pragma unroll
    for (int r = 0; r < 4; ++r) {
        pp[l15 * 36 + quad * 4 + r]      = o0[r];
        pp[l15 * 36 + 16 + quad * 4 + r] = o1[r];
    }
    if (quad == 0)
        lsumP[((size_t)sp * 16 + bh) * NPIX + q0 + wv * 16 + l15] = lsum;
    __syncthreads();
    const int q = lane >> 2, off = (lane & 3) * 8;
    float* dst = OtP + (((size_t)sp * 16 + bh) * NPIX + q0 + wv * 16 + q) * 32 + off;
    *(float4*)dst       = *(float4*)&pp[q * 36 + off];
    *((float4*)dst + 1) = *(float4*)&pp[q * 36 + off + 4];
}

// ---------------------------------------------------------------------------
// Kernel 2b: combine splits, normalize, emit fragment-major bf16 OtT.
// grid (9, 16): q = bx*256+tid, bh = by.
// ---------------------------------------------------------------------------
__global__ __launch_bounds__(256) void norm_kernel(
        const float* __restrict__ OtP, const float* __restrict__ lsumP,
        unsigned short* __restrict__ OtT)
{
    const int q = blockIdx.x * 256 + threadIdx.x;
    const int bh = blockIdx.y;
    const float* pa = OtP + ((size_t)bh * NPIX + q) * 32;
    const float* pb = OtP + ((size_t)(16 + bh) * NPIX + q) * 32;
    const float inv = 1.f / (lsumP[(size_t)bh * NPIX + q] +
                             lsumP[(size_t)(16 + bh) * NPIX + q]);
    const int b = bh >> 3, h = bh & 7;
    unsigned short* cell = OtT + (((size_t)b * NGRP + (q >> 4)) * 32 + h * 4) * 128
                         + (q & 15) * 8;
    #pragma unroll
    for (int jq = 0; jq < 4; ++jq) {
        const float4 a0 = *(const float4*)(pa + jq * 8);
        const float4 a1 = *(const float4*)(pa + jq * 8 + 4);
        const float4 b0 = *(const float4*)(pb + jq * 8);
        const float4 b1 = *(const float4*)(pb + jq * 8 + 4);
        const float o0 = (a0.x + b0.x) * inv, o1 = (a0.y + b0.y) * inv;
        const float o2 = (a0.z + b0.z) * inv, o3 = (a0.w + b0.w) * inv;
        const float o4 = (a1.x + b1.x) * inv, o5 = (a1.y + b1.y) * inv;
        const float o6 = (a1.z + b1.z) * inv, o7 = (a1.w + b1.w) * inv;
        *(uint4*)(cell + jq * 128) = make_uint4(pk2(o0, o1), pk2(o2, o3),
                                                pk2(o4, o5), pk2(o6, o7));
    }
}

// ---------------------------------------------------------------------------
// Kernel 3: proj GEMM, streaming + fused bias/residual (unchanged).
// grid (18, 16, 2).
// ---------------------------------------------------------------------------
__global__ __launch_bounds__(256) void proj_gemm(
        const unsigned short* __restrict__ OtT, const unsigned short* __restrict__ wp,
        const float* __restrict__ bias, const float* __restrict__ x,
        float* __restrict__ out)
{
    __shared__ float plds[4][576];
    const int tid = threadIdx.x, wv = tid >> 6, lane = tid & 63;
    const int l15 = lane & 15, quad = lane >> 4;
    const int n0 = blockIdx.x * 128, my = blockIdx.y, b = blockIdx.z;
    const int nw = n0 + wv * 32;

    bf16x8 af[8];
    #pragma unroll
    for (int kc = 0; kc < 8; ++kc)
        af[kc] = *(const bf16x8*)(wp + ((size_t)(my * 32 + kc * 4 + quad) * 16 + l15) * 8);

    f32x4 acc[2];
    acc[0] = (f32x4){0.f, 0.f, 0.f, 0.f};
    acc[1] = (f32x4){0.f, 0.f, 0.f, 0.f};

    #pragma unroll
    for (int sub = 0; sub < 2; ++sub) {
        const int ngrp = (nw + sub * 16) >> 4;
        const unsigned short* bp = OtT + ((size_t)b * NGRP + ngrp) * 32 * 128;
        #pragma unroll
        for (int kc = 0; kc < 8; ++kc) {
            const bf16x8 bf = *(const bf16x8*)(bp + (size_t)(kc * 4 + quad) * 128 + l15 * 8);
            acc[sub] = __builtin_amdgcn_mfma_f32_16x16x32_bf16(af[kc], bf, acc[sub], 0, 0, 0);
        }
    }

    float* wl = plds[wv];
    #pragma unroll
    for (int sub = 0; sub < 2; ++sub) {
        wl[(quad * 4 + 0) * 36 + sub * 16 + l15] = acc[sub][0];
        wl[(quad * 4 + 1) * 36 + sub * 16 + l15] = acc[sub][1];
        wl[(quad * 4 + 2) * 36 + sub * 16 + l15] = acc[sub][2];
        wl[(quad * 4 + 3) * 36 + sub * 16 + l15] = acc[sub][3];
    }
    const int m0 = my * 16;
    #pragma unroll
    for (int p = 0; p < 2; ++p) {
        const int row = p * 8 + (lane >> 3), cn = (lane & 7) * 4;
        const int c = m0 + row;
        const size_t idx = ((size_t)b * C_DIM + c) * NPIX + nw + cn;
        const f32x4 v = *(const f32x4*)&wl[row * 36 + cn];
        const f32x4 r = *(const f32x4*)(x + idx);
        const float bv = bias[c];
        f32x4 o;
        o[0] = v[0] + bv + r[0]; o[1] = v[1] + bv + r[1];
        o[2] = v[2] + bv + r[2]; o[3] = v[3] + bv + r[3];
        *(f32x4*)(out + idx) = o;
    }
}

// ---------------------------------------------------------------------------
extern "C" void kernel_launch(void* const* d_in, const int* in_sizes, int n_in,
                              void* d_out, int out_size, void* d_ws, size_t ws_size,
                              hipStream_t stream)
{
    const float* x      = (const float*)d_in[0];
    const float* w_qkv  = (const float*)d_in[1];
    const float* b_qkv  = (const float*)d_in[2];
    const float* w_proj = (const float*)d_in[3];
    const float* b_proj = (const float*)d_in[4];
    float* out = (float*)d_out;

    unsigned short* ws = (unsigned short*)d_ws;
    unsigned short* xT  = ws + OFF_XT;
    unsigned short* Qg  = ws + OFF_Q;
    unsigned short* Kg  = ws + OFF_K;
    unsigned short* Vg  = ws + OFF_V;
    unsigned short* OtT = ws + OFF_OT;
    unsigned short* wq  = ws + OFF_WQ;
    unsigned short* wp  = ws + OFF_WP;
    float* fws   = (float*)(ws + OFF_F32);
    float* OtP   = fws;                       // 2 x 16 x 2304 x 32 f32
    float* lsumP = fws + 4718592;             // 2 x 16 x 2304 f32

    prep_xt<<<dim3(36, 4, 2), 256, 0, stream>>>(x, xT);
    prep_w<<<dim3(128), 256, 0, stream>>>(w_qkv, w_proj, wq, wp);
    qkv_gemm<<<dim3(9, 24, 2), 256, 0, stream>>>(xT, wq, b_qkv, Qg, Kg, Vg);
    attn_kernel<<<dim3(16, 36, 2), 256, 0, stream>>>(Qg, Kg, Vg, OtP, lsumP);
    norm_kernel<<<dim3(9, 16), 256, 0, stream>>>(OtP, lsumP, OtT);
    proj_gemm<<<dim3(18, 16, 2), 256, 0, stream>>>(OtT, wp, b_proj, x, out);
}